// Round 3
// baseline (120.678 us; speedup 1.0000x reference)
//
#include <hip/hip_runtime.h>
#include <hip/hip_bf16.h>

#define HH 256
#define WW 256
#define NPIX (HH*WW)
#define NS 512
#define PSTRIDE 12                  // floats per stroke in packed params
#define L2_SLOT   (NS*PSTRIDE)      // float slot in ws for the l2 accumulator
#define FLAG_SLOT (NS*PSTRIDE + 1)  // 1.0 = inputs are bf16, 0.0 = inputs are f32

__device__ __forceinline__ float bf2f(__hip_bfloat16 v) { return __bfloat162float(v); }

// ---------------------------------------------------------------------------
// Kernel 0: dtype sniff (insurance). Read sigma as bf16; EVEN-index elements
// are real sigma values iff the data is truly bf16 (if data is f32, even bf16
// elements are low mantissa halves -> implausible). Also zero l2 accum.
// ---------------------------------------------------------------------------
__global__ __launch_bounds__(256) void k0_sniff(const void* __restrict__ sigma,
                                                float* __restrict__ wsf)
{
    const __hip_bfloat16* sb = (const __hip_bfloat16*)sigma;
    const int t = threadIdx.x;
    const float v0 = bf2f(sb[2*t]);
    const float v1 = bf2f(sb[2*t + 512]);
    const bool ok = (v0 > 0.05f) && (v0 < 1.0f) && (v1 > 0.05f) && (v1 < 1.0f);

    __shared__ float red[256];
    red[t] = ok ? 1.0f : 0.0f;
    __syncthreads();
    for (int off = 128; off > 0; off >>= 1) {
        if (t < off) red[t] = fminf(red[t], red[t + off]);
        __syncthreads();
    }
    if (t == 0) {
        wsf[FLAG_SLOT] = red[0];     // 1.0 -> all plausible -> bf16 inputs
        wsf[L2_SLOT]   = 0.0f;       // ws is poisoned 0xAA; zero the accumulator
    }
}

// ---------------------------------------------------------------------------
// Kernel 1: per-stroke exact discrete min of quad over the grid (analytic
// per-row argmin of the convex quadratic), then pack per-stroke constants:
//   quad(x,y) = (P x + Q y + T1)^2 + (R x + S y + T2)^2
//   k_c = alpha * color_c / (exp(-qmin) + 1e-6)
// One block per stroke; thread i handles row i.
// ---------------------------------------------------------------------------
__global__ __launch_bounds__(256) void k1_prep(
    const void* __restrict__ offset,
    const void* __restrict__ sigma,
    const void* __restrict__ theta,
    const void* __restrict__ color,
    const void* __restrict__ alpha,
    float* __restrict__ wsf)
{
    const int n = blockIdx.x;
    const int i = threadIdx.x;          // row index

    const bool isbf = (wsf[FLAG_SLOT] > 0.5f);
    float ox, oy, s0, s1, th, c0, c1, c2, al;
    if (isbf) {
        const __hip_bfloat16* ob = (const __hip_bfloat16*)offset;
        const __hip_bfloat16* sb = (const __hip_bfloat16*)sigma;
        const __hip_bfloat16* tb = (const __hip_bfloat16*)theta;
        const __hip_bfloat16* cb = (const __hip_bfloat16*)color;
        const __hip_bfloat16* ab = (const __hip_bfloat16*)alpha;
        ox = bf2f(ob[2*n]);   oy = bf2f(ob[2*n+1]);
        s0 = bf2f(sb[2*n]);   s1 = bf2f(sb[2*n+1]);
        th = bf2f(tb[n]);
        c0 = bf2f(cb[3*n]);   c1 = bf2f(cb[3*n+1]);  c2 = bf2f(cb[3*n+2]);
        al = bf2f(ab[n]);
    } else {
        const float* of = (const float*)offset;
        const float* sf = (const float*)sigma;
        const float* tf = (const float*)theta;
        const float* cf = (const float*)color;
        const float* af = (const float*)alpha;
        ox = of[2*n];   oy = of[2*n+1];
        s0 = sf[2*n];   s1 = sf[2*n+1];
        th = tf[n];
        c0 = cf[3*n];   c1 = cf[3*n+1];  c2 = cf[3*n+2];
        al = af[n];
    }

    const float ratio = (float)WW / (float)HH;   // = 1 here, kept for fidelity
    const float sx = s0 / ratio;
    const float sy = s1;
    const float a = 1.0f / (2.0f * sx * sx);
    const float b = 1.0f / (2.0f * sy * sy);

    float s, c;
    __sincosf(th, &s, &c);
    const float ra = sqrtf(a), rb = sqrtf(b);
    // rot = [[c,-s],[s,-c]]:  u = c(x-ox) - s(y-oy);  v = s(x-ox) - c(y-oy)
    const float P = ra * c,  Q = -ra * s,  T1 = ra * (-c * ox + s * oy);
    const float R = rb * s,  S = -rb * c,  T2 = rb * (-s * ox + c * oy);

    // row-min: q(x) = (P x + beta)^2 + (R x + delta)^2, convex in x
    const float y     = (float)i / (float)HH;
    const float beta  = fmaf(Q, y, T1);
    const float delta = fmaf(S, y, T2);
    const float A  = P * P + R * R;            // >= min(a,b) > 0
    const float Bh = P * beta + R * delta;
    const float xstar = -Bh / A;
    int j0 = (int)floorf(xstar * (float)WW);
    j0 = max(0, min(WW - 1, j0));
    const int j1 = min(WW - 1, j0 + 1);
    const float x0 = (float)j0 / (float)WW, x1 = (float)j1 / (float)WW;
    const float u0 = fmaf(P, x0, beta),  v0 = fmaf(R, x0, delta);
    const float u1 = fmaf(P, x1, beta),  v1 = fmaf(R, x1, delta);
    const float qrow = fminf(u0*u0 + v0*v0, u1*u1 + v1*v1);

    __shared__ float red[256];
    red[i] = qrow;
    __syncthreads();
    for (int off = 128; off > 0; off >>= 1) {
        if (i < off) red[i] = fminf(red[i], red[i + off]);
        __syncthreads();
    }

    if (i == 0) {
        const float qmin   = red[0];
        const float maxpdf = __expf(-qmin);
        const float inv    = 1.0f / (maxpdf + 1e-6f);
        const float base   = al * inv;
        float* p = wsf + n * PSTRIDE;
        p[0] = P;  p[1] = Q;  p[2] = T1;
        p[3] = R;  p[4] = S;  p[5] = T2;
        p[6] = base * c0;
        p[7] = base * c1;
        p[8] = base * c2;
        p[9] = 0.0f; p[10] = 0.0f; p[11] = 0.0f;
    }
}

// ---------------------------------------------------------------------------
// Kernel 2: one thread per pixel; loop all 512 strokes with wave-uniform
// param loads. Fused sigmoid epilogue, f32 store, and (out-target)^2 partial
// reduction -> one atomicAdd/block.  OUTPUT IS FLOAT32 (reference dtype).
// ---------------------------------------------------------------------------
__global__ __launch_bounds__(256) void k2_paint(
    const void* __restrict__ canvas,
    const void* __restrict__ target,
    const float* __restrict__ wsf,
    float* __restrict__ out,
    float* __restrict__ l2_accum)
{
    const int p = blockIdx.x * 256 + threadIdx.x;
    const int i = p >> 8;           // row
    const int j = p & 255;          // col
    const float x = (float)j * (1.0f / (float)WW);
    const float y = (float)i * (1.0f / (float)HH);
    const bool isbf = (wsf[FLAG_SLOT] > 0.5f);

    float a0 = 0.0f, a1 = 0.0f, a2 = 0.0f;
    const float4* __restrict__ p4 = (const float4*)wsf;

    #pragma unroll 4
    for (int n = 0; n < NS; ++n) {
        const float4 f0 = p4[3*n];      // P, Q, T1, R
        const float4 f1 = p4[3*n + 1];  // S, T2, k0, k1
        const float4 f2 = p4[3*n + 2];  // k2, pad...
        float U = fmaf(f0.x, x, fmaf(f0.y, y, f0.z));
        float V = fmaf(f0.w, x, fmaf(f1.x, y, f1.y));
        float q = fmaf(V, V, U * U);
        float e = __expf(-q);
        a0 = fmaf(e, f1.z, a0);
        a1 = fmaf(e, f1.w, a1);
        a2 = fmaf(e, f2.x, a2);
    }

    float cv0, cv1, cv2, t0, t1, t2;
    if (isbf) {
        const __hip_bfloat16* cb = (const __hip_bfloat16*)canvas;
        const __hip_bfloat16* tb = (const __hip_bfloat16*)target;
        cv0 = bf2f(cb[p]);  cv1 = bf2f(cb[NPIX + p]);  cv2 = bf2f(cb[2*NPIX + p]);
        t0  = bf2f(tb[p]);  t1  = bf2f(tb[NPIX + p]);  t2  = bf2f(tb[2*NPIX + p]);
    } else {
        const float* cf = (const float*)canvas;
        const float* tf = (const float*)target;
        cv0 = cf[p];  cv1 = cf[NPIX + p];  cv2 = cf[2*NPIX + p];
        t0  = tf[p];  t1  = tf[NPIX + p];  t2  = tf[2*NPIX + p];
    }

    const float z0 = cv0 + a0;
    const float z1 = cv1 + a1;
    const float z2 = cv2 + a2;
    const float o0 = 1.0f / (1.0f + __expf(-z0));
    const float o1 = 1.0f / (1.0f + __expf(-z1));
    const float o2 = 1.0f / (1.0f + __expf(-z2));
    out[p]          = o0;
    out[NPIX + p]   = o1;
    out[2*NPIX + p] = o2;

    const float d0 = o0 - t0;
    const float d1 = o1 - t1;
    const float d2 = o2 - t2;
    float l2loc = d0*d0 + d1*d1 + d2*d2;

    __shared__ float red[256];
    red[threadIdx.x] = l2loc;
    __syncthreads();
    for (int off = 128; off > 0; off >>= 1) {
        if (threadIdx.x < off) red[threadIdx.x] += red[threadIdx.x + off];
        __syncthreads();
    }
    if (threadIdx.x == 0) atomicAdd(l2_accum, red[0]);
}

// ---------------------------------------------------------------------------
// Kernel 3: sharpness/transparency reduction over strokes + loss finalize.
// ---------------------------------------------------------------------------
__global__ __launch_bounds__(256) void k3_loss(
    const void* __restrict__ sigma,
    const void* __restrict__ alpha,
    const float* __restrict__ wsf,
    float* __restrict__ out)
{
    const int t = threadIdx.x;
    const bool isbf = (wsf[FLAG_SLOT] > 0.5f);
    float sh = 0.0f, tr = 0.0f;
    for (int n = t; n < NS; n += 256) {
        float s0, s1, al;
        if (isbf) {
            s0 = bf2f(((const __hip_bfloat16*)sigma)[2*n]);
            s1 = bf2f(((const __hip_bfloat16*)sigma)[2*n+1]);
            al = bf2f(((const __hip_bfloat16*)alpha)[n]);
        } else {
            s0 = ((const float*)sigma)[2*n];
            s1 = ((const float*)sigma)[2*n+1];
            al = ((const float*)alpha)[n];
        }
        sh += fabsf(1.0f - s0 / s1);
        tr += fabsf(al);
    }
    __shared__ float r1[256], r2[256];
    r1[t] = sh; r2[t] = tr;
    __syncthreads();
    for (int off = 128; off > 0; off >>= 1) {
        if (t < off) { r1[t] += r1[t + off]; r2[t] += r2[t + off]; }
        __syncthreads();
    }
    if (t == 0) {
        const float sharp  = (r1[0] / (float)NS) * 0.001f;
        const float transp = -(r2[0] / (float)NS) * 0.001f;
        const float l2  = wsf[L2_SLOT] / (float)(3 * NPIX);
        const float mse = l2;
        const float psnr = 10.0f * log10f(1.0f / (mse + 1e-12f));
        const float loss = l2 + transp + sharp - psnr / 30.0f;
        out[3 * NPIX] = loss;
    }
}

// ---------------------------------------------------------------------------
extern "C" void kernel_launch(void* const* d_in, const int* in_sizes, int n_in,
                              void* d_out, int out_size, void* d_ws, size_t ws_size,
                              hipStream_t stream)
{
    const void* canvas = d_in[0];
    const void* target = d_in[1];
    const void* offset = d_in[2];
    const void* sigma  = d_in[3];
    const void* theta  = d_in[4];
    const void* color  = d_in[5];
    const void* alpha  = d_in[6];
    float* out = (float*)d_out;
    float* wsf = (float*)d_ws;

    k0_sniff<<<1, 256, 0, stream>>>(sigma, wsf);
    k1_prep<<<NS, 256, 0, stream>>>(offset, sigma, theta, color, alpha, wsf);
    k2_paint<<<NPIX / 256, 256, 0, stream>>>(canvas, target, wsf, out, wsf + L2_SLOT);
    k3_loss<<<1, 256, 0, stream>>>(sigma, alpha, wsf, out);
}

// Round 4
// 112.148 us; speedup vs baseline: 1.0761x; 1.0761x over previous
//
#include <hip/hip_runtime.h>
#include <hip/hip_bf16.h>

#define HH 256
#define WW 256
#define NPIX (HH*WW)
#define NS 512
#define PSTRIDE 12                  // floats per stroke in packed params
#define L2_SLOT   (NS*PSTRIDE)      // float: l2 atomic accumulator
#define CNT_SLOT  (NS*PSTRIDE + 1)  // int:   block-completion counter

#define BLK 512                     // k2 block: 4 stroke-teams x 128 pixels
#define PXB 128                     // pixels per k2 block
#define TEAMS 4
#define SPT (NS/TEAMS)              // strokes per team = 128
#define K2_GRID (NPIX/PXB)          // 512 blocks

#define L2E 1.4426950408889634f     // log2(e)

#if __has_builtin(__builtin_amdgcn_exp2f)
#define EXP2F(x) __builtin_amdgcn_exp2f(x)
#else
#define EXP2F(x) exp2f(x)
#endif
#if __has_builtin(__builtin_amdgcn_rcpf)
#define RCPF(x) __builtin_amdgcn_rcpf(x)
#else
#define RCPF(x) (1.0f/(x))
#endif

// ---------------------------------------------------------------------------
// Kernel 1: per-stroke constants, pre-scaled by log2(e) so k2 uses raw exp2:
//   q2(x,y) = (P x + Q y + T1)^2 + (R x + S y + T2)^2   ( = log2(e) * quad )
//   pdf = exp2(-q2);  k_c = alpha*color_c/(exp2(-q2min)+1e-6)
// Exact discrete max via per-row analytic argmin of the convex quadratic.
// Also stashes per-stroke |1-s0/s1| and |alpha| in pad slots, and block 0
// zeroes the l2 accumulator + completion counter (ws is poisoned 0xAA).
// ---------------------------------------------------------------------------
__global__ __launch_bounds__(256) void k1_prep(
    const float* __restrict__ offset, const float* __restrict__ sigma,
    const float* __restrict__ theta,  const float* __restrict__ color,
    const float* __restrict__ alpha,  float* __restrict__ wsf)
{
    const int n = blockIdx.x;
    const int i = threadIdx.x;          // row index

    const float ox = offset[2*n], oy = offset[2*n+1];
    const float s0 = sigma[2*n],  s1 = sigma[2*n+1];
    const float th = theta[n];

    // ratio = W/H = 1; sx = s0/ratio, sy = s1.  Scaled: ra = sqrt(L2E/(2 sx^2))
    const float k  = sqrtf(0.5f * L2E);
    const float ra = k / s0;
    const float rb = k / s1;

    float s, c;
    __sincosf(th, &s, &c);
    // rot = [[c,-s],[s,-c]]:  u = c(x-ox) - s(y-oy);  v = s(x-ox) - c(y-oy)
    const float P = ra * c,  Q = -ra * s,  T1 = ra * (-c * ox + s * oy);
    const float R = rb * s,  S = -rb * c,  T2 = rb * (-s * ox + c * oy);

    // row-min of q2(x) = (P x + beta)^2 + (R x + delta)^2 (convex in x)
    const float y     = (float)i / (float)HH;
    const float beta  = fmaf(Q, y, T1);
    const float delta = fmaf(S, y, T2);
    const float A     = P * P + R * R;          // > 0
    const float xstar = -(P * beta + R * delta) / A;
    int j0 = (int)floorf(xstar * (float)WW);
    j0 = max(0, min(WW - 1, j0));
    const int j1 = min(WW - 1, j0 + 1);
    const float x0 = (float)j0 / (float)WW, x1 = (float)j1 / (float)WW;
    const float u0 = fmaf(P, x0, beta),  v0 = fmaf(R, x0, delta);
    const float u1 = fmaf(P, x1, beta),  v1 = fmaf(R, x1, delta);
    float q = fminf(u0*u0 + v0*v0, u1*u1 + v1*v1);

    #pragma unroll
    for (int off = 32; off > 0; off >>= 1)
        q = fminf(q, __shfl_down(q, off));
    __shared__ float wmin[4];
    if ((i & 63) == 0) wmin[i >> 6] = q;
    __syncthreads();

    if (i == 0) {
        const float qmin   = fminf(fminf(wmin[0], wmin[1]), fminf(wmin[2], wmin[3]));
        const float maxpdf = EXP2F(-qmin);
        const float base   = alpha[n] / (maxpdf + 1e-6f);
        float* p = wsf + n * PSTRIDE;
        p[0] = P;  p[1] = Q;  p[2] = T1;
        p[3] = R;  p[4] = S;  p[5] = T2;
        p[6] = base * color[3*n];
        p[7] = base * color[3*n+1];
        p[8] = base * color[3*n+2];
        p[9]  = fabsf(1.0f - s0 / s1);   // sharpness term
        p[10] = fabsf(alpha[n]);         // transparency term
        p[11] = 0.0f;
        if (n == 0) {
            wsf[L2_SLOT] = 0.0f;
            ((int*)wsf)[CNT_SLOT] = 0;
        }
    }
}

// ---------------------------------------------------------------------------
// Kernel 2: 512 blocks x 512 threads = 16 waves/CU (4/SIMD) for latency
// hiding. Each block: 128 pixels x 4 stroke-teams of 128 strokes; LDS
// cross-team reduce; team 0 does sigmoid + f32 store + l2 partial; last
// block (atomic counter) finalizes the scalar loss.
// ---------------------------------------------------------------------------
__global__ __launch_bounds__(512, 4) void k2_paint(
    const float* __restrict__ canvas, const float* __restrict__ target,
    float* __restrict__ wsf, float* __restrict__ out)
{
    const int tid  = threadIdx.x;
    const int team = tid >> 7;          // 0..3
    const int lp   = tid & 127;         // pixel within block
    const int p    = blockIdx.x * PXB + lp;
    const float x  = (float)(p & 255) * (1.0f / (float)WW);
    const float y  = (float)(p >> 8)  * (1.0f / (float)HH);

    const float4* __restrict__ p4 = (const float4*)wsf;
    const int base3 = team * SPT * 3;

    float a0 = 0.0f, a1 = 0.0f, a2 = 0.0f;
    #pragma unroll 4
    for (int n = 0; n < SPT; ++n) {
        const float4 f0 = p4[base3 + 3*n];      // P, Q, T1, R
        const float4 f1 = p4[base3 + 3*n + 1];  // S, T2, k0, k1
        const float4 f2 = p4[base3 + 3*n + 2];  // k2, sh, tr, pad
        const float U = fmaf(f0.x, x, fmaf(f0.y, y, f0.z));
        const float V = fmaf(f0.w, x, fmaf(f1.x, y, f1.y));
        const float q = fmaf(V, V, U * U);
        const float e = EXP2F(-q);
        a0 = fmaf(e, f1.z, a0);
        a1 = fmaf(e, f1.w, a1);
        a2 = fmaf(e, f2.x, a2);
    }

    __shared__ float red[3][BLK];
    red[0][tid] = a0;  red[1][tid] = a1;  red[2][tid] = a2;
    __syncthreads();

    float l2loc = 0.0f;
    if (tid < PXB) {
        const float t0 = red[0][tid] + red[0][tid+128] + red[0][tid+256] + red[0][tid+384];
        const float t1 = red[1][tid] + red[1][tid+128] + red[1][tid+256] + red[1][tid+384];
        const float t2 = red[2][tid] + red[2][tid+128] + red[2][tid+256] + red[2][tid+384];
        const float z0 = canvas[p]          + t0;
        const float z1 = canvas[NPIX + p]   + t1;
        const float z2 = canvas[2*NPIX + p] + t2;
        const float o0 = RCPF(1.0f + EXP2F(-z0 * L2E));
        const float o1 = RCPF(1.0f + EXP2F(-z1 * L2E));
        const float o2 = RCPF(1.0f + EXP2F(-z2 * L2E));
        out[p]          = o0;
        out[NPIX + p]   = o1;
        out[2*NPIX + p] = o2;
        const float d0 = o0 - target[p];
        const float d1 = o1 - target[NPIX + p];
        const float d2 = o2 - target[2*NPIX + p];
        l2loc = d0*d0 + d1*d1 + d2*d2;
        #pragma unroll
        for (int off = 32; off > 0; off >>= 1)
            l2loc += __shfl_down(l2loc, off);
    }
    __shared__ float lw[2];
    __shared__ int sdone;
    if (tid < PXB && (tid & 63) == 0) lw[tid >> 6] = l2loc;
    __syncthreads();

    if (tid == 0) {
        atomicAdd(&wsf[L2_SLOT], lw[0] + lw[1]);
        __threadfence();
        const int old = atomicAdd((int*)wsf + CNT_SLOT, 1);
        sdone = (old == K2_GRID - 1) ? 1 : 0;
    }
    __syncthreads();

    if (sdone) {  // exactly one block runs this, after all l2 adds are visible
        float sh = wsf[tid * PSTRIDE + 9];
        float tr = wsf[tid * PSTRIDE + 10];
        #pragma unroll
        for (int off = 32; off > 0; off >>= 1) {
            sh += __shfl_down(sh, off);
            tr += __shfl_down(tr, off);
        }
        if ((tid & 63) == 0) { red[0][tid >> 6] = sh; red[1][tid >> 6] = tr; }
        __syncthreads();
        if (tid == 0) {
            float shs = 0.0f, trs = 0.0f;
            #pragma unroll
            for (int w = 0; w < 8; ++w) { shs += red[0][w]; trs += red[1][w]; }
            const float l2tot  = atomicAdd(&wsf[L2_SLOT], 0.0f);  // coherent read
            const float l2     = l2tot / (float)(3 * NPIX);
            const float sharp  = (shs / (float)NS) * 0.001f;
            const float transp = -(trs / (float)NS) * 0.001f;
            const float psnr   = 10.0f * log10f(1.0f / (l2 + 1e-12f));
            out[3 * NPIX] = l2 + transp + sharp - psnr / 30.0f;
        }
    }
}

// ---------------------------------------------------------------------------
extern "C" void kernel_launch(void* const* d_in, const int* in_sizes, int n_in,
                              void* d_out, int out_size, void* d_ws, size_t ws_size,
                              hipStream_t stream)
{
    const float* canvas = (const float*)d_in[0];
    const float* target = (const float*)d_in[1];
    const float* offset = (const float*)d_in[2];
    const float* sigma  = (const float*)d_in[3];
    const float* theta  = (const float*)d_in[4];
    const float* color  = (const float*)d_in[5];
    const float* alpha  = (const float*)d_in[6];
    float* out = (float*)d_out;
    float* wsf = (float*)d_ws;

    k1_prep<<<NS, 256, 0, stream>>>(offset, sigma, theta, color, alpha, wsf);
    k2_paint<<<K2_GRID, BLK, 0, stream>>>(canvas, target, wsf, out);
}

// Round 5
// 91.193 us; speedup vs baseline: 1.3233x; 1.2298x over previous
//
#include <hip/hip_runtime.h>
#include <hip/hip_bf16.h>

#define HH 256
#define WW 256
#define NPIX (HH*WW)
#define NS 512
#define PSTRIDE 12                  // floats per stroke in packed params
#define L2_SLOT   (NS*PSTRIDE)      // float: l2 atomic accumulator
#define CNT_SLOT  (NS*PSTRIDE + 1)  // int:   block-completion counter

#define TEAMS 8                     // stroke teams per block (= waves)
#define SPT   (NS/TEAMS)            // strokes per team = 64
#define PPT   4                     // pixels per thread (same row, stride 64)
#define BLK   512                   // 8 waves
#define K2_GRID 256                 // one block per image row

#define L2E 1.4426950408889634f     // log2(e)

#if __has_builtin(__builtin_amdgcn_exp2f)
#define EXP2F(x) __builtin_amdgcn_exp2f(x)
#else
#define EXP2F(x) exp2f(x)
#endif
#if __has_builtin(__builtin_amdgcn_rcpf)
#define RCPF(x) __builtin_amdgcn_rcpf(x)
#else
#define RCPF(x) (1.0f/(x))
#endif

// ---------------------------------------------------------------------------
// Kernel 1: per-stroke constants, pre-scaled by log2(e) so k2 uses raw exp2:
//   q2(x,y) = (P x + Q y + T1)^2 + (R x + S y + T2)^2   ( = log2(e) * quad )
//   pdf = exp2(-q2);  k_c = alpha*color_c/(exp2(-q2min)+1e-6)
// Exact discrete max via per-row analytic argmin of the convex quadratic.
// ---------------------------------------------------------------------------
__global__ __launch_bounds__(256) void k1_prep(
    const float* __restrict__ offset, const float* __restrict__ sigma,
    const float* __restrict__ theta,  const float* __restrict__ color,
    const float* __restrict__ alpha,  float* __restrict__ wsf)
{
    const int n = blockIdx.x;
    const int i = threadIdx.x;          // row index

    const float ox = offset[2*n], oy = offset[2*n+1];
    const float s0 = sigma[2*n],  s1 = sigma[2*n+1];
    const float th = theta[n];

    const float kk = sqrtf(0.5f * L2E);
    const float ra = kk / s0;           // ratio = W/H = 1
    const float rb = kk / s1;

    float s, c;
    __sincosf(th, &s, &c);
    // rot = [[c,-s],[s,-c]]:  u = c(x-ox) - s(y-oy);  v = s(x-ox) - c(y-oy)
    const float P = ra * c,  Q = -ra * s,  T1 = ra * (-c * ox + s * oy);
    const float R = rb * s,  S = -rb * c,  T2 = rb * (-s * ox + c * oy);

    // row-min of q2(x) = (P x + beta)^2 + (R x + delta)^2 (convex in x)
    const float y     = (float)i / (float)HH;
    const float beta  = fmaf(Q, y, T1);
    const float delta = fmaf(S, y, T2);
    const float A     = P * P + R * R;
    const float xstar = -(P * beta + R * delta) / A;
    int j0 = (int)floorf(xstar * (float)WW);
    j0 = max(0, min(WW - 1, j0));
    const int j1 = min(WW - 1, j0 + 1);
    const float x0 = (float)j0 / (float)WW, x1 = (float)j1 / (float)WW;
    const float u0 = fmaf(P, x0, beta),  v0 = fmaf(R, x0, delta);
    const float u1 = fmaf(P, x1, beta),  v1 = fmaf(R, x1, delta);
    float q = fminf(u0*u0 + v0*v0, u1*u1 + v1*v1);

    #pragma unroll
    for (int off = 32; off > 0; off >>= 1)
        q = fminf(q, __shfl_down(q, off));
    __shared__ float wmin[4];
    if ((i & 63) == 0) wmin[i >> 6] = q;
    __syncthreads();

    if (i == 0) {
        const float qmin   = fminf(fminf(wmin[0], wmin[1]), fminf(wmin[2], wmin[3]));
        const float maxpdf = EXP2F(-qmin);
        const float base   = alpha[n] / (maxpdf + 1e-6f);
        float* p = wsf + n * PSTRIDE;
        p[0] = P;  p[1] = Q;  p[2] = T1;
        p[3] = R;  p[4] = S;  p[5] = T2;
        p[6] = base * color[3*n];
        p[7] = base * color[3*n+1];
        p[8] = base * color[3*n+2];
        p[9]  = fabsf(1.0f - s0 / s1);   // sharpness term
        p[10] = fabsf(alpha[n]);         // transparency term
        p[11] = 0.0f;
        if (n == 0) {
            wsf[L2_SLOT] = 0.0f;
            ((int*)wsf)[CNT_SLOT] = 0;
        }
    }
}

// ---------------------------------------------------------------------------
// Kernel 2: 256 blocks (one row each) x 512 threads (8 waves = 8 stroke-teams
// of 64 strokes). Each thread computes 4 pixels (stride 64 in the row),
// amortizing the per-stroke parameter reads 4x. team is readfirstlane'd so
// the param addresses are provably wave-uniform -> scalar s_load (params in
// SGPRs, no per-lane VGPR writeback). LDS cross-team reduce, fused sigmoid
// epilogue + l2 partial, last block finalizes the scalar loss.
// ---------------------------------------------------------------------------
__global__ __launch_bounds__(512) void k2_paint(
    const float* __restrict__ canvas, const float* __restrict__ target,
    const float* __restrict__ prm,    float* __restrict__ out,
    float* __restrict__ l2acc,        int* __restrict__ cnt)
{
    const int tid  = threadIdx.x;
    const int t    = tid & 63;                                  // lane = pixel-thread
    const int team = __builtin_amdgcn_readfirstlane(tid >> 6);  // wave id, scalar
    const int row  = blockIdx.x;
    const float y  = (float)row * (1.0f / (float)HH);

    float xk[PPT];
    #pragma unroll
    for (int k = 0; k < PPT; ++k) xk[k] = (float)(t + 64*k) * (1.0f / (float)WW);

    const float* __restrict__ tp = prm + team * (SPT * PSTRIDE);

    float acc[PPT][3] = {};
    #pragma unroll 2
    for (int n = 0; n < SPT; ++n) {
        const float* sp = tp + n * PSTRIDE;
        const float P  = sp[0], Q  = sp[1], T1 = sp[2];
        const float R  = sp[3], S  = sp[4], T2 = sp[5];
        const float c0 = sp[6], c1 = sp[7], c2 = sp[8];
        const float beta  = fmaf(Q, y, T1);
        const float delta = fmaf(S, y, T2);
        #pragma unroll
        for (int k = 0; k < PPT; ++k) {
            const float U = fmaf(P, xk[k], beta);
            const float V = fmaf(R, xk[k], delta);
            const float e = EXP2F(-fmaf(U, U, V * V));
            acc[k][0] = fmaf(e, c0, acc[k][0]);
            acc[k][1] = fmaf(e, c1, acc[k][1]);
            acc[k][2] = fmaf(e, c2, acc[k][2]);
        }
    }

    // LDS cross-team reduce: [team][pixel 256][ch 3] (stride-3 -> conflict-free)
    __shared__ float sacc[TEAMS][WW][3];
    #pragma unroll
    for (int k = 0; k < PPT; ++k) {
        sacc[team][t + 64*k][0] = acc[k][0];
        sacc[team][t + 64*k][1] = acc[k][1];
        sacc[team][t + 64*k][2] = acc[k][2];
    }
    __syncthreads();

    __shared__ float lw[4];
    __shared__ int sdone;
    if (tid < WW) {
        float z0 = 0.0f, z1 = 0.0f, z2 = 0.0f;
        #pragma unroll
        for (int tm = 0; tm < TEAMS; ++tm) {
            z0 += sacc[tm][tid][0];
            z1 += sacc[tm][tid][1];
            z2 += sacc[tm][tid][2];
        }
        const int p = row * WW + tid;
        z0 += canvas[p];
        z1 += canvas[NPIX + p];
        z2 += canvas[2*NPIX + p];
        const float o0 = RCPF(1.0f + EXP2F(-z0 * L2E));
        const float o1 = RCPF(1.0f + EXP2F(-z1 * L2E));
        const float o2 = RCPF(1.0f + EXP2F(-z2 * L2E));
        out[p]          = o0;
        out[NPIX + p]   = o1;
        out[2*NPIX + p] = o2;
        const float d0 = o0 - target[p];
        const float d1 = o1 - target[NPIX + p];
        const float d2 = o2 - target[2*NPIX + p];
        float l2loc = d0*d0 + d1*d1 + d2*d2;
        #pragma unroll
        for (int off = 32; off > 0; off >>= 1)
            l2loc += __shfl_down(l2loc, off);
        if (t == 0) lw[tid >> 6] = l2loc;
    }
    __syncthreads();

    if (tid == 0) {
        atomicAdd(l2acc, lw[0] + lw[1] + lw[2] + lw[3]);
        __threadfence();
        const int old = atomicAdd(cnt, 1);
        sdone = (old == K2_GRID - 1) ? 1 : 0;
    }
    __syncthreads();

    if (sdone) {  // exactly one block, after all l2 adds are visible
        float sh = prm[tid * PSTRIDE + 9];
        float tr = prm[tid * PSTRIDE + 10];
        #pragma unroll
        for (int off = 32; off > 0; off >>= 1) {
            sh += __shfl_down(sh, off);
            tr += __shfl_down(tr, off);
        }
        if (t == 0) { sacc[0][tid >> 6][0] = sh; sacc[0][tid >> 6][1] = tr; }
        __syncthreads();
        if (tid == 0) {
            float shs = 0.0f, trs = 0.0f;
            #pragma unroll
            for (int w = 0; w < TEAMS; ++w) { shs += sacc[0][w][0]; trs += sacc[0][w][1]; }
            const float l2tot  = atomicAdd(l2acc, 0.0f);  // coherent read
            const float l2     = l2tot / (float)(3 * NPIX);
            const float sharp  = (shs / (float)NS) * 0.001f;
            const float transp = -(trs / (float)NS) * 0.001f;
            const float psnr   = 10.0f * log10f(1.0f / (l2 + 1e-12f));
            out[3 * NPIX] = l2 + transp + sharp - psnr / 30.0f;
        }
    }
}

// ---------------------------------------------------------------------------
extern "C" void kernel_launch(void* const* d_in, const int* in_sizes, int n_in,
                              void* d_out, int out_size, void* d_ws, size_t ws_size,
                              hipStream_t stream)
{
    const float* canvas = (const float*)d_in[0];
    const float* target = (const float*)d_in[1];
    const float* offset = (const float*)d_in[2];
    const float* sigma  = (const float*)d_in[3];
    const float* theta  = (const float*)d_in[4];
    const float* color  = (const float*)d_in[5];
    const float* alpha  = (const float*)d_in[6];
    float* out = (float*)d_out;
    float* wsf = (float*)d_ws;

    k1_prep<<<NS, 256, 0, stream>>>(offset, sigma, theta, color, alpha, wsf);
    k2_paint<<<K2_GRID, BLK, 0, stream>>>(canvas, target, wsf, out,
                                          wsf + L2_SLOT, (int*)wsf + CNT_SLOT);
}

// Round 6
// 86.861 us; speedup vs baseline: 1.3893x; 1.0499x over previous
//
#include <hip/hip_runtime.h>
#include <hip/hip_bf16.h>

#define HH 256
#define WW 256
#define NPIX (HH*WW)
#define NS 512

// SoA param arrays in ws (each NS floats): P,Q,T1,R,S,T2,c0,c1,c2,sh,tr
#define A_P  0
#define A_Q  1
#define A_T1 2
#define A_R  3
#define A_S  4
#define A_T2 5
#define A_C0 6
#define A_C1 7
#define A_C2 8
#define A_SH 9
#define A_TR 10
#define L2_SLOT  (11*NS)
#define CNT_SLOT (11*NS + 1)

#define TEAMS 8                     // waves per k2 block, each owns 64 strokes
#define SPT   (NS/TEAMS)            // 64 strokes per team
#define PPT   4                     // pixels per thread (one row, stride 64)
#define BLK   512
#define K2_GRID 256                 // one block per image row

#define L2E 1.4426950408889634f     // log2(e)

#if __has_builtin(__builtin_amdgcn_exp2f)
#define EXP2F(x) __builtin_amdgcn_exp2f(x)
#else
#define EXP2F(x) exp2f(x)
#endif
#if __has_builtin(__builtin_amdgcn_rcpf)
#define RCPF(x) __builtin_amdgcn_rcpf(x)
#else
#define RCPF(x) (1.0f/(x))
#endif

// ---------------------------------------------------------------------------
// Kernel 1: per-stroke constants, pre-scaled by log2(e) so k2 uses raw exp2:
//   q2(x,y) = (P x + Q y + T1)^2 + (R x + S y + T2)^2   ( = log2(e) * quad )
//   pdf = exp2(-q2);  k_c = alpha*color_c/(exp2(-q2min)+1e-6)
// Exact discrete max via per-row analytic argmin of the convex quadratic.
// Output is SoA so k2's staging loads coalesce.
// ---------------------------------------------------------------------------
__global__ __launch_bounds__(256) void k1_prep(
    const float* __restrict__ offset, const float* __restrict__ sigma,
    const float* __restrict__ theta,  const float* __restrict__ color,
    const float* __restrict__ alpha,  float* __restrict__ wsf)
{
    const int n = blockIdx.x;
    const int i = threadIdx.x;          // row index

    const float ox = offset[2*n], oy = offset[2*n+1];
    const float s0 = sigma[2*n],  s1 = sigma[2*n+1];
    const float th = theta[n];

    const float kk = sqrtf(0.5f * L2E);
    const float ra = kk / s0;           // ratio = W/H = 1
    const float rb = kk / s1;

    float s, c;
    __sincosf(th, &s, &c);
    // rot = [[c,-s],[s,-c]]:  u = c(x-ox) - s(y-oy);  v = s(x-ox) - c(y-oy)
    const float P = ra * c,  Q = -ra * s,  T1 = ra * (-c * ox + s * oy);
    const float R = rb * s,  S = -rb * c,  T2 = rb * (-s * ox + c * oy);

    // row-min of q2(x) = (P x + beta)^2 + (R x + delta)^2 (convex in x)
    const float y     = (float)i / (float)HH;
    const float beta  = fmaf(Q, y, T1);
    const float delta = fmaf(S, y, T2);
    const float A     = P * P + R * R;
    const float xstar = -(P * beta + R * delta) / A;
    int j0 = (int)floorf(xstar * (float)WW);
    j0 = max(0, min(WW - 1, j0));
    const int j1 = min(WW - 1, j0 + 1);
    const float x0 = (float)j0 / (float)WW, x1 = (float)j1 / (float)WW;
    const float u0 = fmaf(P, x0, beta),  v0 = fmaf(R, x0, delta);
    const float u1 = fmaf(P, x1, beta),  v1 = fmaf(R, x1, delta);
    float q = fminf(u0*u0 + v0*v0, u1*u1 + v1*v1);

    #pragma unroll
    for (int off = 32; off > 0; off >>= 1)
        q = fminf(q, __shfl_down(q, off));
    __shared__ float wmin[4];
    if ((i & 63) == 0) wmin[i >> 6] = q;
    __syncthreads();

    if (i == 0) {
        const float qmin   = fminf(fminf(wmin[0], wmin[1]), fminf(wmin[2], wmin[3]));
        const float maxpdf = EXP2F(-qmin);
        const float base   = alpha[n] / (maxpdf + 1e-6f);
        wsf[A_P *NS + n] = P;
        wsf[A_Q *NS + n] = Q;
        wsf[A_T1*NS + n] = T1;
        wsf[A_R *NS + n] = R;
        wsf[A_S *NS + n] = S;
        wsf[A_T2*NS + n] = T2;
        wsf[A_C0*NS + n] = base * color[3*n];
        wsf[A_C1*NS + n] = base * color[3*n+1];
        wsf[A_C2*NS + n] = base * color[3*n+2];
        wsf[A_SH*NS + n] = fabsf(1.0f - s0 / s1);   // sharpness term
        wsf[A_TR*NS + n] = fabsf(alpha[n]);         // transparency term
        if (n == 0) {
            wsf[L2_SLOT] = 0.0f;
            ((int*)wsf)[CNT_SLOT] = 0;
        }
    }
}

// ---------------------------------------------------------------------------
// Kernel 2: 256 blocks (one row each) x 512 threads (8 waves). Stage phase:
// each thread folds one stroke's row-dependent terms (y is block-uniform) and
// writes an 8-float record {P,R,beta,delta,c0,c1,c2,0} to LDS. Inner loop:
// each wave owns 64 strokes, reads records via 2x ds_read_b128 broadcast
// (conflict-free, off the vector-memory pipe), 4 pixels per thread. LDS
// cross-team reduce, fused sigmoid epilogue + l2 partial, last block
// finalizes the scalar loss.
// ---------------------------------------------------------------------------
__global__ __launch_bounds__(512) void k2_paint(
    const float* __restrict__ canvas, const float* __restrict__ target,
    const float* __restrict__ prm,    float* __restrict__ out,
    float* __restrict__ l2acc,        int* __restrict__ cnt)
{
    const int tid  = threadIdx.x;
    const int t    = tid & 63;          // lane
    const int team = tid >> 6;          // wave id 0..7
    const int row  = blockIdx.x;
    const float y  = (float)row * (1.0f / (float)HH);

    __shared__ float sprm[NS * 8];           // 16 KB stroke records
    __shared__ float sacc[TEAMS][WW][3];     // 24 KB partial accumulators

    // ---- stage: one stroke per thread, coalesced SoA reads ----
    {
        const int n = tid;
        const float P  = prm[A_P *NS + n];
        const float Q  = prm[A_Q *NS + n];
        const float T1 = prm[A_T1*NS + n];
        const float R  = prm[A_R *NS + n];
        const float S  = prm[A_S *NS + n];
        const float T2 = prm[A_T2*NS + n];
        const float c0 = prm[A_C0*NS + n];
        const float c1 = prm[A_C1*NS + n];
        const float c2 = prm[A_C2*NS + n];
        float4* sp4 = (float4*)(sprm + n * 8);
        sp4[0] = make_float4(P, R, fmaf(Q, y, T1), fmaf(S, y, T2));
        sp4[1] = make_float4(c0, c1, c2, 0.0f);
    }
    __syncthreads();

    float xk[PPT];
    #pragma unroll
    for (int k = 0; k < PPT; ++k) xk[k] = (float)(t + 64*k) * (1.0f / (float)WW);

    float acc[PPT][3] = {};
    const float4* __restrict__ tp4 = (const float4*)sprm + team * SPT * 2;

    #pragma unroll 4
    for (int n = 0; n < SPT; ++n) {
        const float4 g0 = tp4[2*n];      // P, R, beta, delta  (broadcast)
        const float4 g1 = tp4[2*n + 1];  // c0, c1, c2, 0      (broadcast)
        #pragma unroll
        for (int k = 0; k < PPT; ++k) {
            const float U = fmaf(g0.x, xk[k], g0.z);
            const float V = fmaf(g0.y, xk[k], g0.w);
            const float e = EXP2F(-fmaf(U, U, V * V));
            acc[k][0] = fmaf(e, g1.x, acc[k][0]);
            acc[k][1] = fmaf(e, g1.y, acc[k][1]);
            acc[k][2] = fmaf(e, g1.z, acc[k][2]);
        }
    }

    // ---- cross-team reduce in LDS ----
    #pragma unroll
    for (int k = 0; k < PPT; ++k) {
        sacc[team][t + 64*k][0] = acc[k][0];
        sacc[team][t + 64*k][1] = acc[k][1];
        sacc[team][t + 64*k][2] = acc[k][2];
    }
    __syncthreads();

    __shared__ float lw[4];
    __shared__ int sdone;
    if (tid < WW) {
        float z0 = 0.0f, z1 = 0.0f, z2 = 0.0f;
        #pragma unroll
        for (int tm = 0; tm < TEAMS; ++tm) {
            z0 += sacc[tm][tid][0];
            z1 += sacc[tm][tid][1];
            z2 += sacc[tm][tid][2];
        }
        const int p = row * WW + tid;
        z0 += canvas[p];
        z1 += canvas[NPIX + p];
        z2 += canvas[2*NPIX + p];
        const float o0 = RCPF(1.0f + EXP2F(-z0 * L2E));
        const float o1 = RCPF(1.0f + EXP2F(-z1 * L2E));
        const float o2 = RCPF(1.0f + EXP2F(-z2 * L2E));
        out[p]          = o0;
        out[NPIX + p]   = o1;
        out[2*NPIX + p] = o2;
        const float d0 = o0 - target[p];
        const float d1 = o1 - target[NPIX + p];
        const float d2 = o2 - target[2*NPIX + p];
        float l2loc = d0*d0 + d1*d1 + d2*d2;
        #pragma unroll
        for (int off = 32; off > 0; off >>= 1)
            l2loc += __shfl_down(l2loc, off);
        if (t == 0) lw[tid >> 6] = l2loc;
    }
    __syncthreads();

    if (tid == 0) {
        atomicAdd(l2acc, lw[0] + lw[1] + lw[2] + lw[3]);
        __threadfence();
        const int old = atomicAdd(cnt, 1);
        sdone = (old == K2_GRID - 1) ? 1 : 0;
    }
    __syncthreads();

    if (sdone) {  // exactly one block, after all l2 adds are visible
        float sh = prm[A_SH*NS + tid];
        float tr = prm[A_TR*NS + tid];
        #pragma unroll
        for (int off = 32; off > 0; off >>= 1) {
            sh += __shfl_down(sh, off);
            tr += __shfl_down(tr, off);
        }
        if (t == 0) { sacc[0][team][0] = sh; sacc[0][team][1] = tr; }
        __syncthreads();
        if (tid == 0) {
            float shs = 0.0f, trs = 0.0f;
            #pragma unroll
            for (int w = 0; w < TEAMS; ++w) { shs += sacc[0][w][0]; trs += sacc[0][w][1]; }
            const float l2tot  = atomicAdd(l2acc, 0.0f);  // coherent read
            const float l2     = l2tot / (float)(3 * NPIX);
            const float sharp  = (shs / (float)NS) * 0.001f;
            const float transp = -(trs / (float)NS) * 0.001f;
            const float psnr   = 10.0f * log10f(1.0f / (l2 + 1e-12f));
            out[3 * NPIX] = l2 + transp + sharp - psnr / 30.0f;
        }
    }
}

// ---------------------------------------------------------------------------
extern "C" void kernel_launch(void* const* d_in, const int* in_sizes, int n_in,
                              void* d_out, int out_size, void* d_ws, size_t ws_size,
                              hipStream_t stream)
{
    const float* canvas = (const float*)d_in[0];
    const float* target = (const float*)d_in[1];
    const float* offset = (const float*)d_in[2];
    const float* sigma  = (const float*)d_in[3];
    const float* theta  = (const float*)d_in[4];
    const float* color  = (const float*)d_in[5];
    const float* alpha  = (const float*)d_in[6];
    float* out = (float*)d_out;
    float* wsf = (float*)d_ws;

    k1_prep<<<NS, 256, 0, stream>>>(offset, sigma, theta, color, alpha, wsf);
    k2_paint<<<K2_GRID, BLK, 0, stream>>>(canvas, target, wsf, out,
                                          wsf + L2_SLOT, (int*)wsf + CNT_SLOT);
}

// Round 7
// 86.244 us; speedup vs baseline: 1.3993x; 1.0072x over previous
//
#include <hip/hip_runtime.h>
#include <hip/hip_bf16.h>

#define HH 256
#define WW 256
#define NPIX (HH*WW)
#define NS 512

// SoA param arrays in ws (each NS floats)
#define A_P  0
#define A_Q  1
#define A_T1 2
#define A_R  3
#define A_S  4
#define A_T2 5
#define A_C0 6
#define A_C1 7
#define A_C2 8
#define A_SH 9
#define A_TR 10
#define L2_SLOT  (11*NS)
#define CNT_SLOT (11*NS + 1)

#define TEAMS 16                    // waves per k2 block
#define SPT   (NS/TEAMS)            // 32 strokes per wave, one per lane (<32)
#define PPT   4                     // pixels per thread (one row, stride 64)
#define BLK   1024                  // 16 waves -> 4 waves/SIMD at 1 block/CU
#define K2_GRID 256                 // one block per image row

#define L2E 1.4426950408889634f     // log2(e)

#if __has_builtin(__builtin_amdgcn_exp2f)
#define EXP2F(x) __builtin_amdgcn_exp2f(x)
#else
#define EXP2F(x) exp2f(x)
#endif
#if __has_builtin(__builtin_amdgcn_rcpf)
#define RCPF(x) __builtin_amdgcn_rcpf(x)
#else
#define RCPF(x) (1.0f/(x))
#endif

__device__ __forceinline__ float rlane(float v, int l) {
#if __has_builtin(__builtin_amdgcn_readlane)
    return __int_as_float(__builtin_amdgcn_readlane(__float_as_int(v), l));
#else
    return __shfl(v, l, 64);
#endif
}

// ---------------------------------------------------------------------------
// Kernel 1: per-stroke constants, pre-scaled by log2(e) so k2 uses raw exp2:
//   q2(x,y) = (P x + Q y + T1)^2 + (R x + S y + T2)^2   ( = log2(e) * quad )
//   pdf = exp2(-q2);  k_c = alpha*color_c/(exp2(-q2min)+1e-6)
// Exact discrete max via per-row analytic argmin of the convex quadratic.
// ---------------------------------------------------------------------------
__global__ __launch_bounds__(256) void k1_prep(
    const float* __restrict__ offset, const float* __restrict__ sigma,
    const float* __restrict__ theta,  const float* __restrict__ color,
    const float* __restrict__ alpha,  float* __restrict__ wsf)
{
    const int n = blockIdx.x;
    const int i = threadIdx.x;          // row index

    const float ox = offset[2*n], oy = offset[2*n+1];
    const float s0 = sigma[2*n],  s1 = sigma[2*n+1];
    const float th = theta[n];

    const float kk = sqrtf(0.5f * L2E);
    const float ra = kk / s0;           // ratio = W/H = 1
    const float rb = kk / s1;

    float s, c;
    __sincosf(th, &s, &c);
    // rot = [[c,-s],[s,-c]]:  u = c(x-ox) - s(y-oy);  v = s(x-ox) - c(y-oy)
    const float P = ra * c,  Q = -ra * s,  T1 = ra * (-c * ox + s * oy);
    const float R = rb * s,  S = -rb * c,  T2 = rb * (-s * ox + c * oy);

    // row-min of q2(x) = (P x + beta)^2 + (R x + delta)^2 (convex in x)
    const float y     = (float)i / (float)HH;
    const float beta  = fmaf(Q, y, T1);
    const float delta = fmaf(S, y, T2);
    const float A     = P * P + R * R;
    const float xstar = -(P * beta + R * delta) / A;
    int j0 = (int)floorf(xstar * (float)WW);
    j0 = max(0, min(WW - 1, j0));
    const int j1 = min(WW - 1, j0 + 1);
    const float x0 = (float)j0 / (float)WW, x1 = (float)j1 / (float)WW;
    const float u0 = fmaf(P, x0, beta),  v0 = fmaf(R, x0, delta);
    const float u1 = fmaf(P, x1, beta),  v1 = fmaf(R, x1, delta);
    float q = fminf(u0*u0 + v0*v0, u1*u1 + v1*v1);

    #pragma unroll
    for (int off = 32; off > 0; off >>= 1)
        q = fminf(q, __shfl_down(q, off));
    __shared__ float wmin[4];
    if ((i & 63) == 0) wmin[i >> 6] = q;
    __syncthreads();

    if (i == 0) {
        const float qmin   = fminf(fminf(wmin[0], wmin[1]), fminf(wmin[2], wmin[3]));
        const float maxpdf = EXP2F(-qmin);
        const float base   = alpha[n] / (maxpdf + 1e-6f);
        wsf[A_P *NS + n] = P;
        wsf[A_Q *NS + n] = Q;
        wsf[A_T1*NS + n] = T1;
        wsf[A_R *NS + n] = R;
        wsf[A_S *NS + n] = S;
        wsf[A_T2*NS + n] = T2;
        wsf[A_C0*NS + n] = base * color[3*n];
        wsf[A_C1*NS + n] = base * color[3*n+1];
        wsf[A_C2*NS + n] = base * color[3*n+2];
        wsf[A_SH*NS + n] = fabsf(1.0f - s0 / s1);   // sharpness term
        wsf[A_TR*NS + n] = fabsf(alpha[n]);         // transparency term
        if (n == 0) {
            wsf[L2_SLOT] = 0.0f;
            ((int*)wsf)[CNT_SLOT] = 0;
        }
    }
}

// ---------------------------------------------------------------------------
// Kernel 2: 256 blocks (one row each) x 1024 threads (16 waves = 4/SIMD).
// Each wave owns 32 strokes; lane l<32 holds stroke (wave*32+l)'s 7-float
// record {P,R,beta,delta,c0,c1,c2} in REGISTERS (beta/delta fold the
// block-uniform row y). Inner loop: v_readlane broadcast of lane n's record
// (VALU pipe only -- ZERO memory ops per iteration), 4 pixels per thread.
// LDS cross-team reduce, fused sigmoid epilogue + l2 partial, last block
// finalizes the scalar loss.
// ---------------------------------------------------------------------------
__global__ __launch_bounds__(1024) void k2_paint(
    const float* __restrict__ canvas, const float* __restrict__ target,
    const float* __restrict__ prm,    float* __restrict__ out,
    float* __restrict__ l2acc,        int* __restrict__ cnt)
{
    const int tid  = threadIdx.x;
    const int t    = tid & 63;          // lane
    const int w    = tid >> 6;          // wave id 0..15 (= stroke team)
    const int row  = blockIdx.x;
    const float y  = (float)row * (1.0f / (float)HH);

    // ---- stage: lane l<32 loads stroke (w*SPT + l) into registers ----
    float rP = 0.0f, rR = 0.0f, rB = 0.0f, rD = 0.0f;
    float rc0 = 0.0f, rc1 = 0.0f, rc2 = 0.0f;
    if (t < SPT) {
        const int n = w * SPT + t;
        rP  = prm[A_P *NS + n];
        rR  = prm[A_R *NS + n];
        rB  = fmaf(prm[A_Q*NS + n], y, prm[A_T1*NS + n]);
        rD  = fmaf(prm[A_S*NS + n], y, prm[A_T2*NS + n]);
        rc0 = prm[A_C0*NS + n];
        rc1 = prm[A_C1*NS + n];
        rc2 = prm[A_C2*NS + n];
    }

    float xk[PPT];
    #pragma unroll
    for (int k = 0; k < PPT; ++k) xk[k] = (float)(t + 64*k) * (1.0f / (float)WW);

    float acc[PPT][3] = {};
    #pragma unroll
    for (int n = 0; n < SPT; ++n) {     // full unroll -> immediate-lane readlane
        const float P  = rlane(rP,  n);
        const float R  = rlane(rR,  n);
        const float B  = rlane(rB,  n);
        const float D  = rlane(rD,  n);
        const float c0 = rlane(rc0, n);
        const float c1 = rlane(rc1, n);
        const float c2 = rlane(rc2, n);
        #pragma unroll
        for (int k = 0; k < PPT; ++k) {
            const float U = fmaf(P, xk[k], B);
            const float V = fmaf(R, xk[k], D);
            const float e = EXP2F(-fmaf(U, U, V * V));
            acc[k][0] = fmaf(e, c0, acc[k][0]);
            acc[k][1] = fmaf(e, c1, acc[k][1]);
            acc[k][2] = fmaf(e, c2, acc[k][2]);
        }
    }

    // ---- cross-team reduce in LDS ([team][px][ch], stride-3 = 2-way free) --
    __shared__ float sacc[TEAMS][WW][3];     // 48 KB
    #pragma unroll
    for (int k = 0; k < PPT; ++k) {
        sacc[w][t + 64*k][0] = acc[k][0];
        sacc[w][t + 64*k][1] = acc[k][1];
        sacc[w][t + 64*k][2] = acc[k][2];
    }
    __syncthreads();

    __shared__ float lw[4];
    __shared__ int sdone;
    if (tid < WW) {
        float z0 = 0.0f, z1 = 0.0f, z2 = 0.0f;
        #pragma unroll
        for (int tm = 0; tm < TEAMS; ++tm) {
            z0 += sacc[tm][tid][0];
            z1 += sacc[tm][tid][1];
            z2 += sacc[tm][tid][2];
        }
        const int p = row * WW + tid;
        z0 += canvas[p];
        z1 += canvas[NPIX + p];
        z2 += canvas[2*NPIX + p];
        const float o0 = RCPF(1.0f + EXP2F(-z0 * L2E));
        const float o1 = RCPF(1.0f + EXP2F(-z1 * L2E));
        const float o2 = RCPF(1.0f + EXP2F(-z2 * L2E));
        out[p]          = o0;
        out[NPIX + p]   = o1;
        out[2*NPIX + p] = o2;
        const float d0 = o0 - target[p];
        const float d1 = o1 - target[NPIX + p];
        const float d2 = o2 - target[2*NPIX + p];
        float l2loc = d0*d0 + d1*d1 + d2*d2;
        #pragma unroll
        for (int off = 32; off > 0; off >>= 1)
            l2loc += __shfl_down(l2loc, off);
        if (t == 0) lw[tid >> 6] = l2loc;
    }
    __syncthreads();

    if (tid == 0) {
        atomicAdd(l2acc, lw[0] + lw[1] + lw[2] + lw[3]);
        __threadfence();
        const int old = atomicAdd(cnt, 1);
        sdone = (old == K2_GRID - 1) ? 1 : 0;
    }
    __syncthreads();

    if (sdone) {  // exactly one block, after all l2 adds are visible
        if (tid < NS) {
            float sh = prm[A_SH*NS + tid];
            float tr = prm[A_TR*NS + tid];
            #pragma unroll
            for (int off = 32; off > 0; off >>= 1) {
                sh += __shfl_down(sh, off);
                tr += __shfl_down(tr, off);
            }
            if (t == 0) { sacc[0][w][0] = sh; sacc[0][w][1] = tr; }
        }
        __syncthreads();
        if (tid == 0) {
            float shs = 0.0f, trs = 0.0f;
            #pragma unroll
            for (int v = 0; v < NS/64; ++v) { shs += sacc[0][v][0]; trs += sacc[0][v][1]; }
            const float l2tot  = atomicAdd(l2acc, 0.0f);  // coherent read
            const float l2     = l2tot / (float)(3 * NPIX);
            const float sharp  = (shs / (float)NS) * 0.001f;
            const float transp = -(trs / (float)NS) * 0.001f;
            const float psnr   = 10.0f * log10f(1.0f / (l2 + 1e-12f));
            out[3 * NPIX] = l2 + transp + sharp - psnr / 30.0f;
        }
    }
}

// ---------------------------------------------------------------------------
extern "C" void kernel_launch(void* const* d_in, const int* in_sizes, int n_in,
                              void* d_out, int out_size, void* d_ws, size_t ws_size,
                              hipStream_t stream)
{
    const float* canvas = (const float*)d_in[0];
    const float* target = (const float*)d_in[1];
    const float* offset = (const float*)d_in[2];
    const float* sigma  = (const float*)d_in[3];
    const float* theta  = (const float*)d_in[4];
    const float* color  = (const float*)d_in[5];
    const float* alpha  = (const float*)d_in[6];
    float* out = (float*)d_out;
    float* wsf = (float*)d_ws;

    k1_prep<<<NS, 256, 0, stream>>>(offset, sigma, theta, color, alpha, wsf);
    k2_paint<<<K2_GRID, BLK, 0, stream>>>(canvas, target, wsf, out,
                                          wsf + L2_SLOT, (int*)wsf + CNT_SLOT);
}